// Round 16
// baseline (114.689 us; speedup 1.0000x reference)
//
#include <hip/hip_runtime.h>
#include <hip/hip_bf16.h>

#define B_ 2
#define S_ 2048
#define D_ 1024
#define H_ 16
#define DEPTH_ 64

typedef __attribute__((ext_vector_type(4))) float f32x4;
typedef __attribute__((ext_vector_type(16))) float f32x16;
typedef __attribute__((ext_vector_type(8))) short bf16x8;
typedef __attribute__((ext_vector_type(2))) int i32x2;
typedef const __attribute__((address_space(1))) unsigned int gu32;
typedef __attribute__((address_space(3))) unsigned int lu32;

__device__ __forceinline__ void gload_lds16(const void* g, void* l) {
  __builtin_amdgcn_global_load_lds((gu32*)g, (lu32*)l, 16, 0, 0);
}

__device__ __forceinline__ short f2bf(float f) {
  union { float f; unsigned u; } v; v.f = f;
  return (short)((v.u + 0x7FFFu + ((v.u >> 16) & 1u)) >> 16);
}
// hardware packed f32x2 -> bf16x2 (RNE), one VALU instr
__device__ __forceinline__ unsigned pk2(float lo, float hi) {
  unsigned r;
  asm("v_cvt_pk_bf16_f32 %0, %1, %2" : "=v"(r) : "v"(lo), "v"(hi));
  return r;
}
// v_permlane32_swap_b32: lane^32 exchange, both outputs useful
__device__ __forceinline__ i32x2 plswap(unsigned a, unsigned b) {
  return __builtin_amdgcn_permlane32_swap((int)a, (int)b, false, false);
}
// raw barrier with compiler memory fence (no implicit vmcnt(0) drain)
#define BARRIER_RAW() do {                      \
  __builtin_amdgcn_sched_barrier(0);            \
  asm volatile("" ::: "memory");                \
  __builtin_amdgcn_s_barrier();                 \
  asm volatile("" ::: "memory");                \
  __builtin_amdgcn_sched_barrier(0);            \
} while (0)

// ---------- fused prep: cast X + transpose Wqkv + transpose Wout ----------
__global__ __launch_bounds__(256) void prep_kernel(
    const float* __restrict__ X, short* __restrict__ Xb,
    const float* __restrict__ Wqkv, short* __restrict__ WqkvT,
    const float* __restrict__ Wout, short* __restrict__ WoutT) {
  __shared__ short tile[32][33];
  const int bid = blockIdx.x, tid = threadIdx.x;
  if (bid < 4096) {
    int i = bid * 256 + tid;
    const float4 v = reinterpret_cast<const float4*>(X)[i];
    short2 a, b;
    *reinterpret_cast<unsigned*>(&a) = pk2(v.x, v.y);
    *reinterpret_cast<unsigned*>(&b) = pk2(v.z, v.w);
    reinterpret_cast<short4*>(Xb)[i] = make_short4(a.x, a.y, b.x, b.y);
  } else {
    const float* W;
    short* WT;
    int N, tb;
    if (bid < 7168) { W = Wqkv; WT = WqkvT; N = 3072; tb = bid - 4096; }
    else            { W = Wout; WT = WoutT; N = 1024; tb = bid - 7168; }
    const int K = 1024;
    const int nblk = N >> 5;
    const int n0 = (tb % nblk) * 32, k0 = (tb / nblk) * 32;
    const int tx = tid & 31, ty = tid >> 5;
#pragma unroll
    for (int j = 0; j < 4; ++j)
      tile[ty + 8 * j][tx] = f2bf(W[(size_t)(k0 + ty + 8 * j) * N + n0 + tx]);
    __syncthreads();
#pragma unroll
    for (int j = 0; j < 4; ++j)
      WT[(size_t)(n0 + ty + 8 * j) * K + k0 + tx] = tile[tx][ty + 8 * j];
  }
}

// ---------- GEMM, 2-phase dbuf + counted-vmcnt raw barriers (T3+T4) ----------
template <int EPI, int BM>
__global__ __launch_bounds__(512) void gemm_bt_kernel(
    const short* __restrict__ A, const short* __restrict__ BT,
    const float* __restrict__ bias,
    short* __restrict__ Qh, short* __restrict__ Kh, short* __restrict__ VTt,
    float* __restrict__ Out, int M, int N, int K) {
  constexpr int MI = BM / 64;
  constexpr int ASZ = BM * 32;
  constexpr int BSZ = 128 * 32;
  __shared__ short smem[2 * ASZ + 2 * BSZ];
  const int bm = blockIdx.y * BM, bn = blockIdx.x * 128;
  const int tid = threadIdx.x;
  const int w = tid >> 6, lane = tid & 63;
  const int wr = w >> 1, wc = w & 1;
  const int lr = lane & 15, lg = lane >> 4;
  const int s_r = lane >> 2, s_c = (lane & 3) * 8;
  f32x4 acc[MI][4] = {};
  const int nk = K >> 5;

  auto stage = [&](int buf, int kt) {
    short* Asb = smem + (buf ? ASZ : 0);
    short* Bsb = smem + 2 * ASZ + (buf ? BSZ : 0);
    if (BM == 128 || w < 4)
      gload_lds16(&A[(size_t)(bm + 16 * w + s_r) * K + kt * 32 + s_c], &Asb[16 * w * 32]);
    gload_lds16(&BT[(size_t)(bn + 16 * w + s_r) * K + kt * 32 + s_c], &Bsb[16 * w * 32]);
  };

  stage(0, 0);
  asm volatile("s_waitcnt vmcnt(0)" ::: "memory");
  BARRIER_RAW();
  int cur = 0;
  for (int kt = 0; kt < nk; ++kt) {
    if (kt + 1 < nk) {
      stage(cur ^ 1, kt + 1);
      if (BM == 128 || w < 4) asm volatile("s_waitcnt vmcnt(2)" ::: "memory");
      else                    asm volatile("s_waitcnt vmcnt(1)" ::: "memory");
    } else {
      asm volatile("s_waitcnt vmcnt(0)" ::: "memory");
    }
    BARRIER_RAW();
    const short* Asb = smem + (cur ? ASZ : 0);
    const short* Bsb = smem + 2 * ASZ + (cur ? BSZ : 0);
    bf16x8 af[MI], bfr[4];
#pragma unroll
    for (int mi = 0; mi < MI; ++mi)
      af[mi] = *reinterpret_cast<const bf16x8*>(&Asb[((BM / 4) * wr + 16 * mi + lr) * 32 + 8 * lg]);
#pragma unroll
    for (int ni = 0; ni < 4; ++ni)
      bfr[ni] = *reinterpret_cast<const bf16x8*>(&Bsb[(64 * wc + 16 * ni + lr) * 32 + 8 * lg]);
#pragma unroll
    for (int mi = 0; mi < MI; ++mi)
#pragma unroll
      for (int ni = 0; ni < 4; ++ni)
        acc[mi][ni] = __builtin_amdgcn_mfma_f32_16x16x32_bf16(af[mi], bfr[ni], acc[mi][ni], 0, 0, 0);
    BARRIER_RAW();
    cur ^= 1;
  }

  if constexpr (EPI == 0) {
    if (bn >= 2 * D_) {
      __syncthreads();
      short* vt = smem;
#pragma unroll
      for (int mi = 0; mi < MI; ++mi)
#pragma unroll
        for (int ni = 0; ni < 4; ++ni)
#pragma unroll
          for (int r = 0; r < 4; r += 2) {
            int row_local = (BM / 4) * wr + 16 * mi + 4 * lg + r;
            int col_local = 64 * wc + 16 * ni + lr;
            float bv = bias[bn + col_local];
            unsigned u = pk2(acc[mi][ni][r] + bv, acc[mi][ni][r + 1] + bv);
            int rsw = row_local ^ ((col_local & 7) << 3);
            *reinterpret_cast<unsigned*>(&vt[col_local * 128 + rsw]) = u;
          }
      __syncthreads();
      const int b = bm >> 11, sbase = bm & (S_ - 1);
#pragma unroll
      for (int p = 0; p < 4; ++p) {
        int slot = 512 * p + tid;
        int vrow = slot >> 4, seg = slot & 15;
        int dd_col = bn - 2 * D_ + vrow;
        int hh = dd_col >> 6, dd = dd_col & 63;
        int csw = (seg * 8) ^ ((vrow & 7) << 3);
        short* dst = &VTt[((size_t)(b * H_ + hh) * DEPTH_ + dd) * S_ + sbase + seg * 8];
        *reinterpret_cast<bf16x8*>(dst) = *reinterpret_cast<const bf16x8*>(&vt[vrow * 128 + csw]);
      }
    } else {
      constexpr float SCQ = 0.125f * 1.44269504f;
#pragma unroll
      for (int mi = 0; mi < MI; ++mi)
#pragma unroll
        for (int ni = 0; ni < 4; ++ni)
#pragma unroll
          for (int r = 0; r < 4; ++r) {
            int row = bm + (BM / 4) * wr + 16 * mi + 4 * lg + r;
            int col = bn + 64 * wc + 16 * ni + lr;
            float v = acc[mi][ni][r] + bias[col];
            int b = row >> 11, s = row & (S_ - 1);
            int which = col >> 10, cm = col & (D_ - 1);
            int hh = cm >> 6, dd = cm & 63;
            size_t bh = (size_t)(b * H_ + hh);
            if (which == 0) Qh[(bh * S_ + s) * DEPTH_ + dd] = f2bf(v * SCQ);
            else            Kh[(bh * S_ + s) * DEPTH_ + dd] = f2bf(v);
          }
    }
  } else {
#pragma unroll
    for (int mi = 0; mi < MI; ++mi)
#pragma unroll
      for (int ni = 0; ni < 4; ++ni)
#pragma unroll
        for (int r = 0; r < 4; ++r) {
          int row = bm + (BM / 4) * wr + 16 * mi + 4 * lg + r;
          int col = bn + 64 * wc + 16 * ni + lr;
          Out[(size_t)row * N + col] = acc[mi][ni][r] + bias[col];
        }
  }
}

// ---------- flash attention: 2048 blocks = 64 q-strips x 32 bh ----------
// Block = one 32-row q-strip; 4 waves = 4 private kv-chunks of 32-kv tiles.
// K region [128][64] chunk-stacked; V region [64][128] slot-interleaved,
// cooperatively staged with per-lane swizzled sources. R14 math per kv.
__global__ __launch_bounds__(256, 4) void attn_kernel(
    const short* __restrict__ Qh, const short* __restrict__ Kh,
    const short* __restrict__ VTt, const float* __restrict__ mask,
    short* __restrict__ ctx) {
  constexpr float LOG2E = 1.44269504f;
  __shared__ short smem[16384];  // 32KB: K [128][64] | V [64][128]
  const int bid = blockIdx.x;
  const int ss = 63 - (bid >> 5);        // heavy-first strip
  const int bh = bid & 31;
  const int b = bh >> 4, h = bh & 15;
  const short* Qp = Qh + (size_t)bh * S_ * DEPTH_;
  const short* Kp = Kh + (size_t)bh * S_ * DEPTH_;
  const short* Vp = VTt + (size_t)bh * DEPTH_ * S_;
  const int tid = threadIdx.x;
  const int w = tid >> 6, lane = tid & 63;
  const int lq = lane & 31, hi = lane >> 5;
  const int q0w = ss * 32;
  const int nt = ss + 1;                 // 32-kv tiles
  const int base = nt >> 2, rem = nt & 3;
  const int mycnt = base + (w < rem ? 1 : 0);
  const int mystart = w * base + (w < rem ? w : rem);
  const int mc = base + (rem ? 1 : 0);
  short* KR = smem;                      // 8192 shorts
  short* VR = smem + 8192;               // 8192 shorts
  const int srw = lane >> 3;             // K stage row 0..7
  const int scs = 8 * ((lane & 7) ^ srw);
  const int vps = lane & 15;             // V physical slot

  bf16x8 qf[4];
#pragma unroll
  for (int ksd = 0; ksd < 4; ++ksd)
    qf[ksd] = *reinterpret_cast<const bf16x8*>(&Qp[(size_t)(q0w + lq) * DEPTH_ + 16 * ksd + 8 * hi]);

  bf16x8 ones = {};
  if (hi == 0) ones[0] = (short)0x3F80;

  f32x16 acc0 = {}, acc1 = {};
  float l_run = 0.f;

  for (int i = 0; i < mc; ++i) {
    __syncthreads();
    // stage own chunk's K tile (32 rows), swizzled source
    if (i < mycnt) {
      const int kc = mystart + i;
#pragma unroll
      for (int jj = 0; jj < 4; ++jj)
        gload_lds16(&Kp[(size_t)(kc * 32 + jj * 8 + srw) * DEPTH_ + scs],
                    &KR[(w * 32 + jj * 8) * 64]);
    }
    // stage V region rows [w*16, w*16+16): slot-interleaved chunks
#pragma unroll
    for (int jj = 0; jj < 4; ++jj) {
      const int r = w * 16 + jj * 4 + (lane >> 4);
      const int ls = vps ^ (r & 7);
      const int c = ls >> 2, g8 = ls & 3;
      const int ccnt = base + (c < rem ? 1 : 0);
      const int cstart = c * base + (c < rem ? c : rem);
      if (i < ccnt) {
        const int kc = cstart + i;
        gload_lds16(&Vp[(size_t)r * S_ + kc * 32 + g8 * 8], &VR[(w * 16 + jj * 4) * 128]);
      }
    }
    __syncthreads();
    if (i >= mycnt) continue;

    const int kt = mystart + i;
    const int k0 = kt * 32;
    // S^T[kv32][q32] in log2 domain (Q pre-scaled)
    f32x16 sc = {};
#pragma unroll
    for (int ksd = 0; ksd < 4; ++ksd) {
      bf16x8 kf = *reinterpret_cast<const bf16x8*>(
          &KR[(w * 32 + lq) * 64 + ((16 * ksd + 8 * hi) ^ ((lq & 7) * 8))]);
      sc = __builtin_amdgcn_mfma_f32_32x32x16_bf16(kf, qf[ksd], sc, 0, 0, 0);
    }
    {
      float mv = mask[(size_t)b * S_ + k0 + lq];
      bf16x8 maf = {};
      if (hi == 0) maf[0] = f2bf(LOG2E * mv);
      sc = __builtin_amdgcn_mfma_f32_32x32x16_bf16(maf, ones, sc, 0, 0, 0);
    }
    if (kt == nt - 1) {
      const int qg = q0w + lq;
#pragma unroll
      for (int r = 0; r < 16; ++r) {
        int kvg = k0 + (r & 3) + 8 * (r >> 2) + 4 * hi;
        if (kvg > qg) sc[r] = -1e30f;
      }
    }
    // shift-free softmax + tree sum + permlane combine
#pragma unroll
    for (int r = 0; r < 16; ++r) sc[r] = exp2f(sc[r]);
    float s8[8];
#pragma unroll
    for (int r = 0; r < 8; ++r) s8[r] = sc[r] + sc[r + 8];
#pragma unroll
    for (int r = 0; r < 4; ++r) s8[r] = s8[r] + s8[r + 4];
    float su = (s8[0] + s8[1]) + (s8[2] + s8[3]);
    {
      union { float f; int i; } sb; sb.f = su;
      i32x2 rs = plswap((unsigned)sb.i, (unsigned)sb.i);
      union { int i; float f; } p0, p1; p0.i = rs[0]; p1.i = rs[1];
      l_run += p0.f + p1.f;
    }
    // PV: pack P, permlane exchange, accumulate ctx^T
#pragma unroll
    for (int ks = 0; ks < 2; ++ks) {
      const int rb = 8 * ks;
      unsigned a = pk2(sc[rb + 0], sc[rb + 1]);
      unsigned bq = pk2(sc[rb + 2], sc[rb + 3]);
      unsigned c = pk2(sc[rb + 4], sc[rb + 5]);
      unsigned d = pk2(sc[rb + 6], sc[rb + 7]);
      i32x2 r02 = plswap(a, c);
      i32x2 r13 = plswap(bq, d);
      union { unsigned u[4]; bf16x8 v; } pf;
      pf.u[0] = (unsigned)r02[0];
      pf.u[1] = (unsigned)r13[0];
      pf.u[2] = (unsigned)r02[1];
      pf.u[3] = (unsigned)r13[1];
#pragma unroll
      for (int dh = 0; dh < 2; ++dh) {
        const int row = dh * 32 + lq;
        const int ps = (4 * w + 2 * ks + hi) ^ (row & 7);
        bf16x8 vf = *reinterpret_cast<const bf16x8*>(&VR[row * 128 + ps * 8]);
        if (dh == 0) acc0 = __builtin_amdgcn_mfma_f32_32x32x16_bf16(vf, pf.v, acc0, 0, 0, 0);
        else         acc1 = __builtin_amdgcn_mfma_f32_32x32x16_bf16(vf, pf.v, acc1, 0, 0, 0);
      }
    }
  }

  // ---- 4-way merge, normalize, transpose, store ----
  __syncthreads();
  float* F  = (float*)smem;              // 3 x 64 x 32 f32 = 24KB
  float* Lp = (float*)(smem + 12288);    // 192 f32
  short* ob = smem + 12672;              // [32 q][72]
  if (w != 0) {
    float* dst = F + ((size_t)(w - 1) * 64 + lane) * 32;
#pragma unroll
    for (int r = 0; r < 16; ++r) { dst[r] = acc0[r]; dst[16 + r] = acc1[r]; }
    Lp[(w - 1) * 64 + lane] = l_run;
  }
  __syncthreads();
  if (w == 0) {
    float lt = l_run;
#pragma unroll
    for (int s = 0; s < 3; ++s) {
      const float* src = F + ((size_t)s * 64 + lane) * 32;
      lt += Lp[s * 64 + lane];
#pragma unroll
      for (int r = 0; r < 16; ++r) { acc0[r] += src[r]; acc1[r] += src[16 + r]; }
    }
    const float rl = 1.f / lt;
#pragma unroll
    for (int dh = 0; dh < 2; ++dh) {
      const f32x16& Aa = dh ? acc1 : acc0;
#pragma unroll
      for (int gg = 0; gg < 4; ++gg)
#pragma unroll
        for (int p = 0; p < 2; ++p) {
          int r0 = 4 * gg + 2 * p;
          int d0 = 2 * p + 8 * gg + 4 * hi + 32 * dh;
          unsigned u = pk2(Aa[r0] * rl, Aa[r0 + 1] * rl);
          *reinterpret_cast<unsigned*>(&ob[lq * 72 + d0]) = u;
        }
    }
  }
  __syncthreads();
  {
    const int row = tid >> 3, seg = tid & 7;
    short* dst = ctx + ((size_t)b * S_ + q0w + row) * D_ + h * 64 + seg * 8;
    *reinterpret_cast<bf16x8*>(dst) = *reinterpret_cast<const bf16x8*>(&ob[row * 72 + seg * 8]);
  }
}

extern "C" void kernel_launch(void* const* d_in, const int* in_sizes, int n_in,
                              void* d_out, int out_size, void* d_ws, size_t ws_size,
                              hipStream_t stream) {
  const float* X    = (const float*)d_in[0];
  const float* mask = (const float*)d_in[1];
  const float* Wqkv = (const float*)d_in[2];
  const float* bqkv = (const float*)d_in[3];
  const float* Wout = (const float*)d_in[4];
  const float* bout = (const float*)d_in[5];
  float* Out = (float*)d_out;

  short* ws    = (short*)d_ws;
  short* Xb    = ws;                                   // 4096*1024 bf16
  short* WqkvT = Xb + (size_t)4096 * 1024;             // [3072][1024]
  short* WoutT = WqkvT + (size_t)3072 * 1024;          // [1024][1024]
  short* Qh    = WoutT + (size_t)1024 * 1024;          // [bh][s][64]
  short* Kh    = Qh + (size_t)B_ * H_ * S_ * DEPTH_;   // [bh][s][64]
  short* VTt   = Kh + (size_t)B_ * H_ * S_ * DEPTH_;   // [bh][64][s]
  short* ctx   = VTt + (size_t)B_ * H_ * S_ * DEPTH_;  // [b][s][1024]

  prep_kernel<<<8192, 256, 0, stream>>>(X, Xb, Wqkv, WqkvT, Wout, WoutT);
  gemm_bt_kernel<0, 128><<<dim3(24, 32), 512, 0, stream>>>(Xb, WqkvT, bqkv, Qh, Kh, VTt, nullptr,
                                                           4096, 3072, 1024);
  attn_kernel<<<2048, 256, 0, stream>>>(Qh, Kh, VTt, mask, ctx);
  gemm_bt_kernel<1, 64><<<dim3(8, 64), 512, 0, stream>>>(ctx, WoutT, bout, nullptr, nullptr, nullptr,
                                                         Out, 4096, 1024, 1024);
}

// Round 17
// 105.846 us; speedup vs baseline: 1.0835x; 1.0835x over previous
//
#include <hip/hip_runtime.h>
#include <hip/hip_bf16.h>

#define B_ 2
#define S_ 2048
#define D_ 1024
#define H_ 16
#define DEPTH_ 64

typedef __attribute__((ext_vector_type(4))) float f32x4;
typedef __attribute__((ext_vector_type(16))) float f32x16;
typedef __attribute__((ext_vector_type(8))) short bf16x8;
typedef __attribute__((ext_vector_type(2))) int i32x2;
typedef const __attribute__((address_space(1))) unsigned int gu32;
typedef __attribute__((address_space(3))) unsigned int lu32;

__device__ __forceinline__ void gload_lds16(const void* g, void* l) {
  __builtin_amdgcn_global_load_lds((gu32*)g, (lu32*)l, 16, 0, 0);
}

__device__ __forceinline__ short f2bf(float f) {
  union { float f; unsigned u; } v; v.f = f;
  return (short)((v.u + 0x7FFFu + ((v.u >> 16) & 1u)) >> 16);
}
// hardware packed f32x2 -> bf16x2 (RNE), one VALU instr
__device__ __forceinline__ unsigned pk2(float lo, float hi) {
  unsigned r;
  asm("v_cvt_pk_bf16_f32 %0, %1, %2" : "=v"(r) : "v"(lo), "v"(hi));
  return r;
}
// v_permlane32_swap_b32: lane^32 exchange, both outputs useful
__device__ __forceinline__ i32x2 plswap(unsigned a, unsigned b) {
  return __builtin_amdgcn_permlane32_swap((int)a, (int)b, false, false);
}
// raw barrier with compiler memory fence (no implicit vmcnt(0) drain)
#define BARRIER_RAW() do {                      \
  __builtin_amdgcn_sched_barrier(0);            \
  asm volatile("" ::: "memory");                \
  __builtin_amdgcn_s_barrier();                 \
  asm volatile("" ::: "memory");                \
  __builtin_amdgcn_sched_barrier(0);            \
} while (0)

// ---------- fused prep: cast X + transpose Wqkv + transpose Wout ----------
__global__ __launch_bounds__(256) void prep_kernel(
    const float* __restrict__ X, short* __restrict__ Xb,
    const float* __restrict__ Wqkv, short* __restrict__ WqkvT,
    const float* __restrict__ Wout, short* __restrict__ WoutT) {
  __shared__ short tile[32][33];
  const int bid = blockIdx.x, tid = threadIdx.x;
  if (bid < 4096) {
    int i = bid * 256 + tid;
    const float4 v = reinterpret_cast<const float4*>(X)[i];
    short2 a, b;
    *reinterpret_cast<unsigned*>(&a) = pk2(v.x, v.y);
    *reinterpret_cast<unsigned*>(&b) = pk2(v.z, v.w);
    reinterpret_cast<short4*>(Xb)[i] = make_short4(a.x, a.y, b.x, b.y);
  } else {
    const float* W;
    short* WT;
    int N, tb;
    if (bid < 7168) { W = Wqkv; WT = WqkvT; N = 3072; tb = bid - 4096; }
    else            { W = Wout; WT = WoutT; N = 1024; tb = bid - 7168; }
    const int K = 1024;
    const int nblk = N >> 5;
    const int n0 = (tb % nblk) * 32, k0 = (tb / nblk) * 32;
    const int tx = tid & 31, ty = tid >> 5;
#pragma unroll
    for (int j = 0; j < 4; ++j)
      tile[ty + 8 * j][tx] = f2bf(W[(size_t)(k0 + ty + 8 * j) * N + n0 + tx]);
    __syncthreads();
#pragma unroll
    for (int j = 0; j < 4; ++j)
      WT[(size_t)(n0 + ty + 8 * j) * K + k0 + tx] = tile[tx][ty + 8 * j];
  }
}

// ---------- GEMM, 2-phase dbuf + counted-vmcnt raw barriers (T3+T4) ----------
template <int EPI, int BM>
__global__ __launch_bounds__(512) void gemm_bt_kernel(
    const short* __restrict__ A, const short* __restrict__ BT,
    const float* __restrict__ bias,
    short* __restrict__ Qh, short* __restrict__ Kh, short* __restrict__ VTt,
    float* __restrict__ Out, int M, int N, int K) {
  constexpr int MI = BM / 64;
  constexpr int ASZ = BM * 32;
  constexpr int BSZ = 128 * 32;
  __shared__ short smem[2 * ASZ + 2 * BSZ];
  const int bm = blockIdx.y * BM, bn = blockIdx.x * 128;
  const int tid = threadIdx.x;
  const int w = tid >> 6, lane = tid & 63;
  const int wr = w >> 1, wc = w & 1;
  const int lr = lane & 15, lg = lane >> 4;
  const int s_r = lane >> 2, s_c = (lane & 3) * 8;
  f32x4 acc[MI][4] = {};
  const int nk = K >> 5;

  auto stage = [&](int buf, int kt) {
    short* Asb = smem + (buf ? ASZ : 0);
    short* Bsb = smem + 2 * ASZ + (buf ? BSZ : 0);
    if (BM == 128 || w < 4)
      gload_lds16(&A[(size_t)(bm + 16 * w + s_r) * K + kt * 32 + s_c], &Asb[16 * w * 32]);
    gload_lds16(&BT[(size_t)(bn + 16 * w + s_r) * K + kt * 32 + s_c], &Bsb[16 * w * 32]);
  };

  stage(0, 0);
  asm volatile("s_waitcnt vmcnt(0)" ::: "memory");
  BARRIER_RAW();
  int cur = 0;
  for (int kt = 0; kt < nk; ++kt) {
    if (kt + 1 < nk) {
      stage(cur ^ 1, kt + 1);
      if (BM == 128 || w < 4) asm volatile("s_waitcnt vmcnt(2)" ::: "memory");
      else                    asm volatile("s_waitcnt vmcnt(1)" ::: "memory");
    } else {
      asm volatile("s_waitcnt vmcnt(0)" ::: "memory");
    }
    BARRIER_RAW();
    const short* Asb = smem + (cur ? ASZ : 0);
    const short* Bsb = smem + 2 * ASZ + (cur ? BSZ : 0);
    bf16x8 af[MI], bfr[4];
#pragma unroll
    for (int mi = 0; mi < MI; ++mi)
      af[mi] = *reinterpret_cast<const bf16x8*>(&Asb[((BM / 4) * wr + 16 * mi + lr) * 32 + 8 * lg]);
#pragma unroll
    for (int ni = 0; ni < 4; ++ni)
      bfr[ni] = *reinterpret_cast<const bf16x8*>(&Bsb[(64 * wc + 16 * ni + lr) * 32 + 8 * lg]);
#pragma unroll
    for (int mi = 0; mi < MI; ++mi)
#pragma unroll
      for (int ni = 0; ni < 4; ++ni)
        acc[mi][ni] = __builtin_amdgcn_mfma_f32_16x16x32_bf16(af[mi], bfr[ni], acc[mi][ni], 0, 0, 0);
    BARRIER_RAW();
    cur ^= 1;
  }

  if constexpr (EPI == 0) {
    if (bn >= 2 * D_) {
      __syncthreads();
      short* vt = smem;
#pragma unroll
      for (int mi = 0; mi < MI; ++mi)
#pragma unroll
        for (int ni = 0; ni < 4; ++ni)
#pragma unroll
          for (int r = 0; r < 4; r += 2) {
            int row_local = (BM / 4) * wr + 16 * mi + 4 * lg + r;
            int col_local = 64 * wc + 16 * ni + lr;
            float bv = bias[bn + col_local];
            unsigned u = pk2(acc[mi][ni][r] + bv, acc[mi][ni][r + 1] + bv);
            int rsw = row_local ^ ((col_local & 7) << 3);
            *reinterpret_cast<unsigned*>(&vt[col_local * 128 + rsw]) = u;
          }
      __syncthreads();
      const int b = bm >> 11, sbase = bm & (S_ - 1);
#pragma unroll
      for (int p = 0; p < 4; ++p) {
        int slot = 512 * p + tid;
        int vrow = slot >> 4, seg = slot & 15;
        int dd_col = bn - 2 * D_ + vrow;
        int hh = dd_col >> 6, dd = dd_col & 63;
        int csw = (seg * 8) ^ ((vrow & 7) << 3);
        short* dst = &VTt[((size_t)(b * H_ + hh) * DEPTH_ + dd) * S_ + sbase + seg * 8];
        *reinterpret_cast<bf16x8*>(dst) = *reinterpret_cast<const bf16x8*>(&vt[vrow * 128 + csw]);
      }
    } else {
      constexpr float SCQ = 0.125f * 1.44269504f;
#pragma unroll
      for (int mi = 0; mi < MI; ++mi)
#pragma unroll
        for (int ni = 0; ni < 4; ++ni)
#pragma unroll
          for (int r = 0; r < 4; ++r) {
            int row = bm + (BM / 4) * wr + 16 * mi + 4 * lg + r;
            int col = bn + 64 * wc + 16 * ni + lr;
            float v = acc[mi][ni][r] + bias[col];
            int b = row >> 11, s = row & (S_ - 1);
            int which = col >> 10, cm = col & (D_ - 1);
            int hh = cm >> 6, dd = cm & 63;
            size_t bh = (size_t)(b * H_ + hh);
            if (which == 0) Qh[(bh * S_ + s) * DEPTH_ + dd] = f2bf(v * SCQ);
            else            Kh[(bh * S_ + s) * DEPTH_ + dd] = f2bf(v);
          }
    }
  } else {
#pragma unroll
    for (int mi = 0; mi < MI; ++mi)
#pragma unroll
      for (int ni = 0; ni < 4; ++ni)
#pragma unroll
        for (int r = 0; r < 4; ++r) {
          int row = bm + (BM / 4) * wr + 16 * mi + 4 * lg + r;
          int col = bn + 64 * wc + 16 * ni + lr;
          Out[(size_t)row * N + col] = acc[mi][ni][r] + bias[col];
        }
  }
}

// ---------- flash attention, 32x32 swapped-operand + split-KV ----------
// R14 kernel verbatim (validated 47.2us): 64-kv tiles, CU-balanced map,
// shift-free softmax, permlane32_swap exchange.
__global__ __launch_bounds__(256, 4) void attn_kernel(
    const short* __restrict__ Qh, const short* __restrict__ Kh,
    const short* __restrict__ VTt, const float* __restrict__ mask,
    short* __restrict__ ctx) {
  constexpr float LOG2E = 1.44269504f;
  __shared__ short smem[16384];  // 32KB: [chunk][K 4096 | V 4096] shorts
  const int bid = blockIdx.x;
  // CU-balanced qt map: stride-8 groups {31-g, 16+g, 15-g, g} sum equally
  const int j = bid >> 5, g = j & 7, rr = j >> 3;
  const int qt = (rr == 0) ? 31 - g : (rr == 1) ? 16 + g : (rr == 2) ? 15 - g : g;
  const int bh = bid & 31;
  const int b = bh >> 4, h = bh & 15;
  const short* Qp = Qh + (size_t)bh * S_ * DEPTH_;
  const short* Kp = Kh + (size_t)bh * S_ * DEPTH_;
  const short* Vp = VTt + (size_t)bh * DEPTH_ * S_;
  const int tid = threadIdx.x;
  const int w = tid >> 6, lane = tid & 63;
  const int sw = w & 1, ch = w >> 1;
  const int lq = lane & 31, hi = lane >> 5;
  const int q0w = qt * 64 + sw * 32;
  const int scs = 8 * ((lane & 7) ^ ((lane >> 3) & 7));
  const int srw = lane >> 3;
  short* Ksc = smem + ch * 8192;
  short* Vsc = Ksc + 4096;

  bf16x8 qf[4];
#pragma unroll
  for (int ksd = 0; ksd < 4; ++ksd)
    qf[ksd] = *reinterpret_cast<const bf16x8*>(&Qp[(size_t)(q0w + lq) * DEPTH_ + 16 * ksd + 8 * hi]);

  bf16x8 ones = {};
  if (hi == 0) ones[0] = (short)0x3F80;

  f32x16 acc0 = {}, acc1 = {};
  float l_run = 0.f;

  const int nt = qt + 1;
  const int nh = (nt + 1) >> 1;
  for (int i = 0; i < nh; ++i) {
    const int kt = ch ? (nh + i) : i;
    const bool valid = kt < nt;
    const int k0 = kt * 64;
    __syncthreads();
    if (valid) {
#pragma unroll
      for (int jj = 0; jj < 4; ++jj) {
        const int brow = sw * 32 + jj * 8;
        gload_lds16(&Kp[(size_t)(k0 + brow + srw) * DEPTH_ + scs], &Ksc[brow * 64]);
        gload_lds16(&Vp[(size_t)(brow + srw) * S_ + k0 + scs], &Vsc[brow * 64]);
      }
    }
    __syncthreads();
    if (!valid) continue;

    // S^T[kv][q] in log2 domain (Q pre-scaled by SC*log2e)
    f32x16 sc[2] = {{}, {}};
#pragma unroll
    for (int h2 = 0; h2 < 2; ++h2) {
#pragma unroll
      for (int ksd = 0; ksd < 4; ++ksd) {
        const int row = h2 * 32 + lq;
        const int col = (16 * ksd + 8 * hi) ^ ((row & 7) * 8);
        bf16x8 kf = *reinterpret_cast<const bf16x8*>(&Ksc[row * 64 + col]);
        sc[h2] = __builtin_amdgcn_mfma_f32_32x32x16_bf16(kf, qf[ksd], sc[h2], 0, 0, 0);
      }
      // + mask[kv]*log2e via one MFMA
      float mv = mask[(size_t)b * S_ + k0 + h2 * 32 + lq];
      bf16x8 maf = {};
      if (hi == 0) maf[0] = f2bf(LOG2E * mv);
      sc[h2] = __builtin_amdgcn_mfma_f32_32x32x16_bf16(maf, ones, sc[h2], 0, 0, 0);
    }
    // causal (diag tile only): kv row per reg = (r&3)+8*(r>>2)+4*hi+32*h2
    if (kt == nt - 1) {
      const int qg = q0w + lq;
#pragma unroll
      for (int h2 = 0; h2 < 2; ++h2)
#pragma unroll
        for (int r = 0; r < 16; ++r) {
          int kvg = k0 + (r & 3) + 8 * (r >> 2) + 4 * hi + 32 * h2;
          if (kvg > qg) sc[h2][r] = -1e30f;
        }
    }
    // shift-free softmax: P = exp2(s), independent across regs; tree sum
#pragma unroll
    for (int h2 = 0; h2 < 2; ++h2)
#pragma unroll
      for (int r = 0; r < 16; ++r) sc[h2][r] = exp2f(sc[h2][r]);
    float s8[8];
#pragma unroll
    for (int r = 0; r < 8; ++r) s8[r] = (sc[0][r] + sc[0][r + 8]) + (sc[1][r] + sc[1][r + 8]);
#pragma unroll
    for (int r = 0; r < 4; ++r) s8[r] = s8[r] + s8[r + 4];
    float su = (s8[0] + s8[1]) + (s8[2] + s8[3]);
    {
      union { float f; int i; } sb; sb.f = su;
      i32x2 rs = plswap((unsigned)sb.i, (unsigned)sb.i);
      union { int i; float f; } p0, p1; p0.i = rs[0]; p1.i = rs[1];
      l_run += p0.f + p1.f;   // su[l] + su[l^32] for all lanes
    }

    // PV: pack P rows into B-frags; partner exchange via permlane32_swap
#pragma unroll
    for (int h2 = 0; h2 < 2; ++h2) {
#pragma unroll
      for (int ks = 0; ks < 2; ++ks) {
        const int rb = 8 * ks;
        unsigned a = pk2(sc[h2][rb + 0], sc[h2][rb + 1]);
        unsigned bq = pk2(sc[h2][rb + 2], sc[h2][rb + 3]);
        unsigned c = pk2(sc[h2][rb + 4], sc[h2][rb + 5]);
        unsigned d = pk2(sc[h2][rb + 6], sc[h2][rb + 7]);
        i32x2 r02 = plswap(a, c);
        i32x2 r13 = plswap(bq, d);
        union { unsigned u[4]; bf16x8 v; } pf;
        pf.u[0] = (unsigned)r02[0];
        pf.u[1] = (unsigned)r13[0];
        pf.u[2] = (unsigned)r02[1];
        pf.u[3] = (unsigned)r13[1];
#pragma unroll
        for (int dh = 0; dh < 2; ++dh) {
          const int row = dh * 32 + lq;
          const int col = (32 * h2 + 16 * ks + 8 * hi) ^ ((row & 7) * 8);
          bf16x8 vf = *reinterpret_cast<const bf16x8*>(&Vsc[row * 64 + col]);
          if (dh == 0) acc0 = __builtin_amdgcn_mfma_f32_32x32x16_bf16(vf, pf.v, acc0, 0, 0, 0);
          else         acc1 = __builtin_amdgcn_mfma_f32_32x32x16_bf16(vf, pf.v, acc1, 0, 0, 0);
        }
      }
    }
  }

  // ---- merge chunks (same shift -> simple add), normalize, transpose, store ----
  __syncthreads();
  float* F  = (float*)smem;
  float* ML = (float*)(smem + 8192);
  short* ob = smem + 8704;
  if (ch == 1) {
    float* dst = F + ((size_t)sw * 64 + lane) * 32;
#pragma unroll
    for (int r = 0; r < 16; ++r) { dst[r] = acc0[r]; dst[16 + r] = acc1[r]; }
    ML[sw * 64 + lane] = l_run;
  }
  __syncthreads();
  if (ch == 0) {
    const float* src = F + ((size_t)sw * 64 + lane) * 32;
    const float rl = 1.f / (l_run + ML[sw * 64 + lane]);
#pragma unroll
    for (int r = 0; r < 16; ++r) {
      acc0[r] = (acc0[r] + src[r]) * rl;
      acc1[r] = (acc1[r] + src[16 + r]) * rl;
    }
#pragma unroll
    for (int dh = 0; dh < 2; ++dh) {
      const f32x16& Aa = dh ? acc1 : acc0;
#pragma unroll
      for (int gg = 0; gg < 4; ++gg)
#pragma unroll
        for (int p = 0; p < 2; ++p) {
          int r0 = 4 * gg + 2 * p;
          int d0 = 2 * p + 8 * gg + 4 * hi + 32 * dh;
          unsigned u = pk2(Aa[r0], Aa[r0 + 1]);
          *reinterpret_cast<unsigned*>(&ob[(sw * 32 + lq) * 72 + d0]) = u;
        }
    }
  }
  __syncthreads();
  {
    const int row = tid >> 2, seg = tid & 3;
    short* dst = ctx + ((size_t)b * S_ + qt * 64 + row) * D_ + h * 64 + seg * 16;
    const short* srcp = &ob[row * 72 + seg * 16];
    *reinterpret_cast<bf16x8*>(dst) = *reinterpret_cast<const bf16x8*>(srcp);
    *reinterpret_cast<bf16x8*>(dst + 8) = *reinterpret_cast<const bf16x8*>(srcp + 8);
  }
}

extern "C" void kernel_launch(void* const* d_in, const int* in_sizes, int n_in,
                              void* d_out, int out_size, void* d_ws, size_t ws_size,
                              hipStream_t stream) {
  const float* X    = (const float*)d_in[0];
  const float* mask = (const float*)d_in[1];
  const float* Wqkv = (const float*)d_in[2];
  const float* bqkv = (const float*)d_in[3];
  const float* Wout = (const float*)d_in[4];
  const float* bout = (const float*)d_in[5];
  float* Out = (float*)d_out;

  short* ws    = (short*)d_ws;
  short* Xb    = ws;                                   // 4096*1024 bf16
  short* WqkvT = Xb + (size_t)4096 * 1024;             // [3072][1024]
  short* WoutT = WqkvT + (size_t)3072 * 1024;          // [1024][1024]
  short* Qh    = WoutT + (size_t)1024 * 1024;          // [bh][s][64]
  short* Kh    = Qh + (size_t)B_ * H_ * S_ * DEPTH_;   // [bh][s][64]
  short* VTt   = Kh + (size_t)B_ * H_ * S_ * DEPTH_;   // [bh][64][s]
  short* ctx   = VTt + (size_t)B_ * H_ * S_ * DEPTH_;  // [b][s][1024]

  prep_kernel<<<8192, 256, 0, stream>>>(X, Xb, Wqkv, WqkvT, Wout, WoutT);
  gemm_bt_kernel<0, 128><<<dim3(24, 32), 512, 0, stream>>>(Xb, WqkvT, bqkv, Qh, Kh, VTt, nullptr,
                                                           4096, 3072, 1024);
  attn_kernel<<<1024, 256, 0, stream>>>(Qh, Kh, VTt, mask, ctx);
  gemm_bt_kernel<1, 64><<<dim3(8, 64), 512, 0, stream>>>(ctx, WoutT, bout, nullptr, nullptr, nullptr,
                                                         Out, 4096, 1024, 1024);
}